// Round 9
// baseline (262.210 us; speedup 1.0000x reference)
//
#include <hip/hip_runtime.h>

#define LAMBD 0.2f
#define KMAX 128
#define KS 64
#define SSA 16     // phase-A support-stability window
#define ACAP 600   // phase-A iteration cap

using half8 = __attribute__((ext_vector_type(8))) _Float16;
using f32x4 = __attribute__((ext_vector_type(4))) float;

__device__ __forceinline__ float sshrink(float v, float thr) {
    float c = fminf(fmaxf(v, -thr), thr);
    return v - c;
}

__device__ __forceinline__ unsigned pack2(_Float16 a, _Float16 b) {
    unsigned short ua = __builtin_bit_cast(unsigned short, a);
    unsigned short ub = __builtin_bit_cast(unsigned short, b);
    return (unsigned)ua | ((unsigned)ub << 16);
}

// ---------------- Kernel 1: fused prep. Block 0: s = 1/sigma_max(D)^2 (power iter).
// Blocks 1..256: Gram row r + cbuf = D^T x.
__global__ __launch_bounds__(256) void prep_all(const float* __restrict__ xg,
                                                const float* __restrict__ Dg,
                                                float* __restrict__ ws,
                                                float* __restrict__ Gfull,
                                                float* __restrict__ cbuf)
{
    const int t = threadIdx.x;
    if (blockIdx.x == 0) {
        __shared__ __align__(16) float Dc[256 * 68];
        __shared__ __align__(16) float Bm[64 * 68];
        __shared__ float vv[64];
        __shared__ float part[4 * 64];
        __shared__ float lamsh;

        for (int i = 0; i < 64; ++i)
            Dc[t * 68 + i] = Dg[i * 256 + t];
        __syncthreads();

        const int ti = t >> 4, tj = t & 15;
        float acc[4][4];
        #pragma unroll
        for (int r = 0; r < 4; ++r)
            #pragma unroll
            for (int c = 0; c < 4; ++c) acc[r][c] = 0.f;
        for (int mm = 0; mm < 256; ++mm) {
            const float4 A = *(const float4*)&Dc[mm * 68 + 4 * ti];
            const float4 Bv = *(const float4*)&Dc[mm * 68 + 4 * tj];
            const float Ae[4] = {A.x, A.y, A.z, A.w};
            const float Be[4] = {Bv.x, Bv.y, Bv.z, Bv.w};
            #pragma unroll
            for (int r = 0; r < 4; ++r)
                #pragma unroll
                for (int c = 0; c < 4; ++c)
                    acc[r][c] += Ae[r] * Be[c];
        }
        #pragma unroll
        for (int r = 0; r < 4; ++r)
            #pragma unroll
            for (int c = 0; c < 4; ++c)
                Bm[(4 * ti + r) * 68 + (4 * tj + c)] = acc[r][c];
        if (t < 64) vv[t] = 0.125f;
        __syncthreads();

        for (int itp = 0; itp < 40; ++itp) {
            const int p = t >> 6, i = t & 63;
            float partial = 0.f;
            #pragma unroll
            for (int jj = 0; jj < 16; ++jj) {
                const int j = p * 16 + jj;
                partial += Bm[j * 68 + i] * vv[j];
            }
            part[p * 64 + i] = partial;
            __syncthreads();
            if (t < 64) {
                float nv = part[t] + part[64 + t] + part[128 + t] + part[192 + t];
                float n2 = nv * nv;
                for (int d = 1; d < 64; d <<= 1) n2 += __shfl_xor(n2, d);
                vv[t] = nv * rsqrtf(n2);
                if (t == 0) lamsh = n2;
            }
            __syncthreads();
        }
        if (t == 0) ws[0] = 1.0f / sqrtf(lamsh);   // s = 1/lambda_max(B)
    } else {
        __shared__ float xsh[4][64];
        const int r = blockIdx.x - 1;
        const int s0 = r * 4;
        xsh[t >> 6][t & 63] = xg[s0 * 64 + t];
        __syncthreads();

        float accG = 0.f, a0 = 0.f, a1 = 0.f, a2 = 0.f, a3 = 0.f;
        #pragma unroll
        for (int i = 0; i < 64; ++i) {
            const float dv = Dg[i * 256 + t];
            const float dr = Dg[i * 256 + r];
            accG += dr * dv;
            a0 += xsh[0][i] * dv;
            a1 += xsh[1][i] * dv;
            a2 += xsh[2][i] * dv;
            a3 += xsh[3][i] * dv;
        }
        Gfull[r * 256 + t] = accG;
        cbuf[(s0 + 0) * 256 + t] = a0;
        cbuf[(s0 + 1) * 256 + t] = a1;
        cbuf[(s0 + 2) * 256 + t] = a2;
        cbuf[(s0 + 3) * 256 + t] = a3;
    }
}

// ---------------- Kernel 2: 2-phase FISTA (MFMA delta-y) + per-wave solve + big-k ------
// Phase A: hi-only W, exit on support+sign stability (SSA iters).
// Transition: acc2 = Wlo * y (one-time rebuild).
// Phase B: hi+lo exact polish, exit on full f16-delta freeze (R7-verified criterion).
__global__ __launch_bounds__(256, 1) void ista_solve(const float* __restrict__ cbuf,
                                                     const float* __restrict__ Gfull,
                                                     const float* __restrict__ ws,
                                                     const float* __restrict__ wg,
                                                     float* __restrict__ out)
{
    __shared__ __align__(16) _Float16 dbuf[2][16][264];
    __shared__ __align__(16) _Float16 ybuf[16][264];
    __shared__ int chgs[4];
    __shared__ __align__(16) float znb[4][264];      // [sample][row]
    __shared__ __align__(16) float GmPool[16640];    // 4 x KS*(KS+1) | KMAX*(KMAX+1)
    __shared__ int   idxPool[256];
    __shared__ float sgnPool[256];
    __shared__ float rhsF[KMAX];
    __shared__ float solF[KMAX];
    __shared__ int   big4[4];
    __shared__ int   kbig;

    const int t = threadIdx.x;
    const int w = t >> 6, l = t & 63;
    const int n = l & 15, kg = l >> 4;
    const int s0 = blockIdx.x * 4;
    const float s = ws[0];
    const float thr = LAMBD * s;
    const float S = 1.0f / 2048.0f;
    const float FLUSH = 6.2e-5f;

    // --- build W = I - s*G fragments from Gfull (fp32 -> f16 hi/lo)
    half8 wh[4][8], wl[4][8];
    #pragma unroll
    for (int a = 0; a < 4; ++a) {
        const int row = 64 * w + 16 * a + n;
        #pragma unroll
        for (int kt = 0; kt < 8; ++kt) {
            const float4 g0 = *(const float4*)&Gfull[row * 256 + kt * 32 + kg * 8];
            const float4 g1 = *(const float4*)&Gfull[row * 256 + kt * 32 + kg * 8 + 4];
            const float ge[8] = {g0.x, g0.y, g0.z, g0.w, g1.x, g1.y, g1.z, g1.w};
            half8 h, lo;
            #pragma unroll
            for (int j = 0; j < 8; ++j) {
                const int col = kt * 32 + kg * 8 + j;
                const float wv = (row == col ? 1.0f : 0.0f) - s * ge[j];
                const _Float16 whj = (_Float16)wv;
                h[j] = whj;
                lo[j] = (_Float16)((wv - (float)whj) * 2048.0f);
            }
            wh[a][kt] = h;
            wl[a][kt] = lo;
        }
    }

    // --- state: y = sum of f16 deltas (drives P); z_old (momentum+chg), z_new; b
    float bv[4][4], y[4][4], zo[4][4], zn[4][4];
    #pragma unroll
    for (int a = 0; a < 4; ++a)
        #pragma unroll
        for (int jj = 0; jj < 4; ++jj) {
            const int row = 64 * w + 16 * a + 4 * kg + jj;
            bv[a][jj] = (n < 4) ? s * cbuf[(s0 + n) * 256 + row] : 0.f;
            y[a][jj] = 0.f;
            zo[a][jj] = 0.f;
        }

    f32x4 acc1[4], acc2[4];
    #pragma unroll
    for (int a = 0; a < 4; ++a) {
        acc1[a] = (f32x4){0.f, 0.f, 0.f, 0.f};
        acc2[a] = (f32x4){0.f, 0.f, 0.f, 0.f};
    }

    float tk = 1.0f;
    int cur = 0, stable = 0;
    bool phase2 = false;
    for (int it = 0; ; ++it) {
        const float tk1 = 0.5f * (1.0f + sqrtf(1.0f + 4.0f * tk * tk));
        const float beta = (tk - 1.0f) / tk1;
        bool anychg = false, anylive = false;
        _Float16 dh16[4][4];
        #pragma unroll
        for (int a = 0; a < 4; ++a)
            #pragma unroll
            for (int jj = 0; jj < 4; ++jj) {
                const float P = acc1[a][jj] + S * acc2[a][jj];   // acc2==0 in phase A
                const float z = sshrink(P + bv[a][jj], thr);
                const float zp = zo[a][jj];
                anychg |= ((z > 0.f) != (zp > 0.f)) | ((z < 0.f) != (zp < 0.f));
                zn[a][jj] = z;
                const float yn = z + beta * (z - zp);
                zo[a][jj] = z;
                const float d = yn - y[a][jj];
                const bool live = fabsf(d) >= FLUSH;
                anylive |= live;
                const _Float16 hd = live ? (_Float16)d : (_Float16)0.0f;
                dh16[a][jj] = hd;
                y[a][jj] += (float)hd;
            }
        tk = tk1;
        if (it == 1000) break;

        const bool flag = phase2 ? anylive : anychg;
        const int anyw = __any(flag);
        if (l == 0) chgs[w] = anyw;
        #pragma unroll
        for (int a = 0; a < 4; ++a) {
            const unsigned lo = pack2(dh16[a][0], dh16[a][1]);
            const unsigned hi = pack2(dh16[a][2], dh16[a][3]);
            *(uint2*)&dbuf[cur][n][64 * w + 16 * a + 4 * kg] = make_uint2(lo, hi);
        }
        __syncthreads();
        const int anyblk = chgs[0] | chgs[1] | chgs[2] | chgs[3];
        if (phase2 && !anyblk) break;                 // exact freeze -> converged
        stable = anyblk ? 0 : stable + 1;

        const bool do_trans = (!phase2) && (stable >= SSA || it >= ACAP);
        if (do_trans) {
            // one-time: acc2 = Wlo * y (y includes this iter's dy)
            #pragma unroll
            for (int a = 0; a < 4; ++a) {
                const unsigned lo = pack2((_Float16)y[a][0], (_Float16)y[a][1]);
                const unsigned hi = pack2((_Float16)y[a][2], (_Float16)y[a][3]);
                *(uint2*)&ybuf[n][64 * w + 16 * a + 4 * kg] = make_uint2(lo, hi);
            }
            __syncthreads();
            half8 yh[8];
            #pragma unroll
            for (int kt = 0; kt < 8; ++kt)
                yh[kt] = *(const half8*)&ybuf[n][kt * 32 + kg * 8];
            #pragma unroll
            for (int kt = 0; kt < 8; ++kt)
                #pragma unroll
                for (int a = 0; a < 4; ++a)
                    acc2[a] = __builtin_amdgcn_mfma_f32_16x16x32_f16(wl[a][kt], yh[kt], acc2[a], 0, 0, 0);
            phase2 = true;
            stable = 0;
        }

        half8 dh[8];
        #pragma unroll
        for (int kt = 0; kt < 8; ++kt)
            dh[kt] = *(const half8*)&dbuf[cur][n][kt * 32 + kg * 8];

        #pragma unroll
        for (int kt = 0; kt < 8; ++kt)
            #pragma unroll
            for (int a = 0; a < 4; ++a)
                acc1[a] = __builtin_amdgcn_mfma_f32_16x16x32_f16(wh[a][kt], dh[kt], acc1[a], 0, 0, 0);
        if (phase2 && !do_trans) {
            #pragma unroll
            for (int kt = 0; kt < 8; ++kt)
                #pragma unroll
                for (int a = 0; a < 4; ++a)
                    acc2[a] = __builtin_amdgcn_mfma_f32_16x16x32_f16(wl[a][kt], dh[kt], acc2[a], 0, 0, 0);
        }
        cur ^= 1;
    }

    // --- share z (z_new) across waves
    if (n < 4) {
        #pragma unroll
        for (int a = 0; a < 4; ++a) {
            float4 v = make_float4(zn[a][0], zn[a][1], zn[a][2], zn[a][3]);
            *(float4*)&znb[n][64 * w + 16 * a + 4 * kg] = v;
        }
    }
    __syncthreads();

    // --- per-wave solve: wave w handles sample s0+w
    const int sample = s0 + w;
    float* Gw = GmPool + w * (KS * (KS + 1));
    int*   idxW = idxPool + w * KS;
    float* sgnW = sgnPool + w * KS;

    const float4 zz = *(const float4*)&znb[w][4 * l];
    const int c0 = zz.x != 0.f, c1 = zz.y != 0.f, c2 = zz.z != 0.f, c3 = zz.w != 0.f;
    const int cnt = c0 + c1 + c2 + c3;
    int scan = cnt;
    for (int d = 1; d < 64; d <<= 1) {
        const int v = __shfl_up(scan, d);
        if (l >= d) scan += v;
    }
    int o = scan - cnt;
    const int k = __shfl(scan, 63);
    if (l == 0) big4[w] = (k > KS) ? 1 : 0;

    if (k == 0) {
        if (l == 0) { out[sample * 2] = 0.f; out[sample * 2 + 1] = 0.f; }
    } else if (k <= KS) {
        if (c0) { idxW[o] = 4 * l + 0; sgnW[o] = zz.x > 0.f ? 1.f : -1.f; ++o; }
        if (c1) { idxW[o] = 4 * l + 1; sgnW[o] = zz.y > 0.f ? 1.f : -1.f; ++o; }
        if (c2) { idxW[o] = 4 * l + 2; sgnW[o] = zz.z > 0.f ? 1.f : -1.f; ++o; }
        if (c3) { idxW[o] = 4 * l + 3; sgnW[o] = zz.w > 0.f ? 1.f : -1.f; ++o; }
        __builtin_amdgcn_wave_barrier();

        const int   ib = idxW[(l < k) ? l : (k - 1)];
        const float sg = (l < k) ? sgnW[l] : 0.f;
        float rhs = (l < k) ? (cbuf[sample * 256 + ib] - LAMBD * sg) : 0.f;

        for (int a = 0; a < k; ++a) {
            const int ra = __shfl(ib, a);
            if (l < k) Gw[a * (KS + 1) + l] = Gfull[ra * 256 + ib];
        }
        __builtin_amdgcn_wave_barrier();

        float dinv = 0.f;
        for (int j = 0; j < k; ++j) {
            const float Gjj = Gw[j * (KS + 1) + j];
            const float Ljj = sqrtf(fmaxf(Gjj, 1e-30f));
            const float iv = 1.0f / Ljj;
            float Laj = 0.f;
            if (l == j) { Gw[j * (KS + 1) + j] = Ljj; dinv = iv; }
            if (l > j && l < k) { Laj = Gw[l * (KS + 1) + j] * iv; Gw[l * (KS + 1) + j] = Laj; }
            __builtin_amdgcn_wave_barrier();
            for (int b = j + 1; b < k; ++b) {
                const float Lbj = Gw[b * (KS + 1) + j];
                if (l >= b && l < k) Gw[l * (KS + 1) + b] -= Laj * Lbj;
            }
            __builtin_amdgcn_wave_barrier();
        }

        float yv = rhs;
        for (int j = 0; j < k; ++j) {
            const float Laj = Gw[l * (KS + 1) + j];
            const float yjf = __shfl(yv, j) * __shfl(dinv, j);
            if (l == j) yv = yjf;
            if (l > j) yv -= Laj * yjf;
        }
        float xv = yv;
        for (int j = k - 1; j >= 0; --j) {
            const float Lja = Gw[j * (KS + 1) + l];
            const float xjf = __shfl(xv, j) * __shfl(dinv, j);
            if (l == j) xv = xjf;
            if (l < j) xv -= Lja * xjf;
        }

        float acc = (l < k) ? wg[ib] * xv : 0.f;
        for (int d = 1; d < 64; d <<= 1) acc += __shfl_xor(acc, d);
        if (l == 0) { out[sample * 2] = acc; out[sample * 2 + 1] = -acc; }
    }
    __syncthreads();

    // --- rare big-k path: block-cooperative, sequential over flagged samples
    for (int sw = 0; sw < 4; ++sw) {
        if (!big4[sw]) continue;
        const int smp = s0 + sw;
        if (w == 0) {
            const float4 z2 = *(const float4*)&znb[sw][4 * l];
            const int d0 = z2.x != 0.f, d1 = z2.y != 0.f, d2 = z2.z != 0.f, d3 = z2.w != 0.f;
            const int cn = d0 + d1 + d2 + d3;
            int sc = cn;
            for (int d = 1; d < 64; d <<= 1) {
                const int v = __shfl_up(sc, d);
                if (l >= d) sc += v;
            }
            int oo = sc - cn;
            int kk = __shfl(sc, 63);
            if (kk > KMAX) kk = KMAX;
            if (l == 0) kbig = kk;
            if (d0) { if (oo < KMAX) { idxPool[oo] = 4 * l + 0; sgnPool[oo] = z2.x > 0.f ? 1.f : -1.f; } ++oo; }
            if (d1) { if (oo < KMAX) { idxPool[oo] = 4 * l + 1; sgnPool[oo] = z2.y > 0.f ? 1.f : -1.f; } ++oo; }
            if (d2) { if (oo < KMAX) { idxPool[oo] = 4 * l + 2; sgnPool[oo] = z2.z > 0.f ? 1.f : -1.f; } ++oo; }
            if (d3) { if (oo < KMAX) { idxPool[oo] = 4 * l + 3; sgnPool[oo] = z2.w > 0.f ? 1.f : -1.f; } ++oo; }
        }
        __syncthreads();
        const int kk = kbig;
        float* Gb = GmPool;

        for (int a = 0; a < kk; ++a) {
            const int ra = idxPool[a];
            for (int b = t; b < kk; b += 256)
                Gb[a * (KMAX + 1) + b] = Gfull[ra * 256 + idxPool[b]];
        }
        for (int a = t; a < kk; a += 256)
            rhsF[a] = cbuf[smp * 256 + idxPool[a]] - LAMBD * sgnPool[a];
        __syncthreads();

        for (int j = 0; j < kk; ++j) {
            const float Ljj = sqrtf(fmaxf(Gb[j * (KMAX + 1) + j], 1e-30f));
            const float inv = 1.0f / Ljj;
            if (t == 0) Gb[j * (KMAX + 1) + j] = Ljj;
            for (int a = j + 1 + t; a < kk; a += 256)
                Gb[a * (KMAX + 1) + j] *= inv;
            __syncthreads();
            for (int b = j + 1; b < kk; ++b) {
                const float Lbj = Gb[b * (KMAX + 1) + j];
                const int a = b + t;
                if (a < kk) Gb[a * (KMAX + 1) + b] -= Gb[a * (KMAX + 1) + j] * Lbj;
            }
            __syncthreads();
        }
        for (int j = 0; j < kk; ++j) {
            const float yj = rhsF[j] / Gb[j * (KMAX + 1) + j];
            if (t == 0) solF[j] = yj;
            for (int a = j + 1 + t; a < kk; a += 256)
                rhsF[a] -= Gb[a * (KMAX + 1) + j] * yj;
            __syncthreads();
        }
        for (int j = kk - 1; j >= 0; --j) {
            const float xj = solF[j] / Gb[j * (KMAX + 1) + j];
            if (t == 0) solF[j] = xj;
            for (int a = t; a < j; a += 256)
                solF[a] -= Gb[j * (KMAX + 1) + a] * xj;
            __syncthreads();
        }
        float acc = 0.f;
        for (int a = t; a < kk; a += 256)
            acc += wg[idxPool[a]] * solF[a];
        for (int d = 1; d < 64; d <<= 1) acc += __shfl_xor(acc, d);
        if (l == 0) rhsF[64 + w] = acc;
        __syncthreads();
        if (t == 0) {
            const float tot = rhsF[64] + rhsF[65] + rhsF[66] + rhsF[67];
            out[smp * 2] = tot;
            out[smp * 2 + 1] = -tot;
        }
        __syncthreads();
    }
}

extern "C" void kernel_launch(void* const* d_in, const int* in_sizes, int n_in,
                              void* d_out, int out_size, void* d_ws, size_t ws_size,
                              hipStream_t stream) {
    const float* x = (const float*)d_in[0];   // (1024, 64)
    const float* D = (const float*)d_in[1];   // (64, 256)
    const float* w = (const float*)d_in[2];   // (256,)
    float* out = (float*)d_out;               // (1024, 2)
    float* ws  = (float*)d_ws;

    float* Gfull = ws + 256;                  // 65536 floats
    float* cbuf  = ws + 256 + 65536;          // 262144 floats

    prep_all<<<257, 256, 0, stream>>>(x, D, ws, Gfull, cbuf);
    ista_solve<<<256, 256, 0, stream>>>(cbuf, Gfull, ws, w, out);
}

// Round 11
// 246.892 us; speedup vs baseline: 1.0620x; 1.0620x over previous
//
#include <hip/hip_runtime.h>

#define LAMBD 0.2f
#define KMAX 128
#define KS 64
#define OS 1.9f      // overstep: any s < 2/L converges to the same lasso minimizer
#define MINIT 48     // minimum iterations before support-stable exit
#define SWIN 24      // support+sign stability window

using half8 = __attribute__((ext_vector_type(8))) _Float16;
using f32x4 = __attribute__((ext_vector_type(4))) float;

__device__ __forceinline__ float sshrink(float v, float thr) {
    float c = fminf(fmaxf(v, -thr), thr);
    return v - c;
}

__device__ __forceinline__ unsigned pack2(_Float16 a, _Float16 b) {
    unsigned short ua = __builtin_bit_cast(unsigned short, a);
    unsigned short ub = __builtin_bit_cast(unsigned short, b);
    return (unsigned)ua | ((unsigned)ub << 16);
}

// ---------------- Kernel 1: fused prep. Block 0: s = OS/sigma_max(D)^2 (power iter).
// Blocks 1..256: Gram row r + cbuf = D^T x.
__global__ __launch_bounds__(256) void prep_all(const float* __restrict__ xg,
                                                const float* __restrict__ Dg,
                                                float* __restrict__ ws,
                                                float* __restrict__ Gfull,
                                                float* __restrict__ cbuf)
{
    const int t = threadIdx.x;
    if (blockIdx.x == 0) {
        __shared__ __align__(16) float Dc[256 * 68];
        __shared__ __align__(16) float Bm[64 * 68];
        __shared__ float vv[64];
        __shared__ float part[4 * 64];
        __shared__ float lamsh;

        for (int i = 0; i < 64; ++i)
            Dc[t * 68 + i] = Dg[i * 256 + t];
        __syncthreads();

        const int ti = t >> 4, tj = t & 15;
        float acc[4][4];
        #pragma unroll
        for (int r = 0; r < 4; ++r)
            #pragma unroll
            for (int c = 0; c < 4; ++c) acc[r][c] = 0.f;
        for (int mm = 0; mm < 256; ++mm) {
            const float4 A = *(const float4*)&Dc[mm * 68 + 4 * ti];
            const float4 Bv = *(const float4*)&Dc[mm * 68 + 4 * tj];
            const float Ae[4] = {A.x, A.y, A.z, A.w};
            const float Be[4] = {Bv.x, Bv.y, Bv.z, Bv.w};
            #pragma unroll
            for (int r = 0; r < 4; ++r)
                #pragma unroll
                for (int c = 0; c < 4; ++c)
                    acc[r][c] += Ae[r] * Be[c];
        }
        #pragma unroll
        for (int r = 0; r < 4; ++r)
            #pragma unroll
            for (int c = 0; c < 4; ++c)
                Bm[(4 * ti + r) * 68 + (4 * tj + c)] = acc[r][c];
        if (t < 64) vv[t] = 0.125f;
        __syncthreads();

        for (int itp = 0; itp < 40; ++itp) {
            const int p = t >> 6, i = t & 63;
            float partial = 0.f;
            #pragma unroll
            for (int jj = 0; jj < 16; ++jj) {
                const int j = p * 16 + jj;
                partial += Bm[j * 68 + i] * vv[j];
            }
            part[p * 64 + i] = partial;
            __syncthreads();
            if (t < 64) {
                float nv = part[t] + part[64 + t] + part[128 + t] + part[192 + t];
                float n2 = nv * nv;
                for (int d = 1; d < 64; d <<= 1) n2 += __shfl_xor(n2, d);
                vv[t] = nv * rsqrtf(n2);
                if (t == 0) lamsh = n2;
            }
            __syncthreads();
        }
        if (t == 0) ws[0] = OS / sqrtf(lamsh);   // s = OS/lambda_max(B)
    } else {
        __shared__ float xsh[4][64];
        const int r = blockIdx.x - 1;
        const int s0 = r * 4;
        xsh[t >> 6][t & 63] = xg[s0 * 64 + t];
        __syncthreads();

        float accG = 0.f, a0 = 0.f, a1 = 0.f, a2 = 0.f, a3 = 0.f;
        #pragma unroll
        for (int i = 0; i < 64; ++i) {
            const float dv = Dg[i * 256 + t];
            const float dr = Dg[i * 256 + r];
            accG += dr * dv;
            a0 += xsh[0][i] * dv;
            a1 += xsh[1][i] * dv;
            a2 += xsh[2][i] * dv;
            a3 += xsh[3][i] * dv;
        }
        Gfull[r * 256 + t] = accG;
        cbuf[(s0 + 0) * 256 + t] = a0;
        cbuf[(s0 + 1) * 256 + t] = a1;
        cbuf[(s0 + 2) * 256 + t] = a2;
        cbuf[(s0 + 3) * 256 + t] = a3;
    }
}

// ---------------- Kernel 2: overstep ISTA (MFMA delta-z) + support-stable exit
//                  + per-wave solve + in-block big-k fallback ----------------
// Exit: support+signs unchanged SWIN iters (after MINIT), or full f16 freeze.
// The refit consumes only support+signs, which stabilize ~iter 24 (R6 evidence).
__global__ __launch_bounds__(256, 1) void ista_solve(const float* __restrict__ cbuf,
                                                     const float* __restrict__ Gfull,
                                                     const float* __restrict__ ws,
                                                     const float* __restrict__ wg,
                                                     float* __restrict__ out)
{
    __shared__ __align__(16) _Float16 dbuf[2][16][264];
    __shared__ int chgs[4];
    __shared__ __align__(16) float znb[4][264];      // [sample][row]
    __shared__ __align__(16) float GmPool[16640];    // 4 x KS*(KS+1) | KMAX*(KMAX+1)
    __shared__ int   idxPool[256];
    __shared__ float sgnPool[256];
    __shared__ float rhsF[KMAX];
    __shared__ float solF[KMAX];
    __shared__ int   big4[4];
    __shared__ int   kbig;

    const int t = threadIdx.x;
    const int w = t >> 6, l = t & 63;
    const int n = l & 15, kg = l >> 4;
    const int s0 = blockIdx.x * 4;
    const float s = ws[0];
    const float thr = LAMBD * s;
    const float S = 1.0f / 2048.0f;
    const float FLUSH = 6.2e-5f;

    // --- build W = I - s*G fragments from Gfull (fp32 -> f16 hi/lo)
    half8 wh[4][8], wl[4][8];
    #pragma unroll
    for (int a = 0; a < 4; ++a) {
        const int row = 64 * w + 16 * a + n;
        #pragma unroll
        for (int kt = 0; kt < 8; ++kt) {
            const float4 g0 = *(const float4*)&Gfull[row * 256 + kt * 32 + kg * 8];
            const float4 g1 = *(const float4*)&Gfull[row * 256 + kt * 32 + kg * 8 + 4];
            const float ge[8] = {g0.x, g0.y, g0.z, g0.w, g1.x, g1.y, g1.z, g1.w};
            half8 h, lo;
            #pragma unroll
            for (int j = 0; j < 8; ++j) {
                const int col = kt * 32 + kg * 8 + j;
                const float wv = (row == col ? 1.0f : 0.0f) - s * ge[j];
                const _Float16 whj = (_Float16)wv;
                h[j] = whj;
                lo[j] = (_Float16)((wv - (float)whj) * 2048.0f);
            }
            wh[a][kt] = h;
            wl[a][kt] = lo;
        }
    }

    // --- state: zacc = sum of f16 deltas (drives P); zo = previous z (signs); zn
    float bv[4][4], zacc[4][4], zo[4][4], zn[4][4];
    #pragma unroll
    for (int a = 0; a < 4; ++a)
        #pragma unroll
        for (int jj = 0; jj < 4; ++jj) {
            const int row = 64 * w + 16 * a + 4 * kg + jj;
            bv[a][jj] = (n < 4) ? s * cbuf[(s0 + n) * 256 + row] : 0.f;
            zacc[a][jj] = 0.f;
            zo[a][jj] = 0.f;
        }

    f32x4 acc1[4], acc2[4];
    #pragma unroll
    for (int a = 0; a < 4; ++a) {
        acc1[a] = (f32x4){0.f, 0.f, 0.f, 0.f};
        acc2[a] = (f32x4){0.f, 0.f, 0.f, 0.f};
    }

    int cur = 0, stable = 0;
    for (int it = 0; ; ++it) {
        bool anychg = false, anylive = false;
        _Float16 dh16[4][4];
        #pragma unroll
        for (int a = 0; a < 4; ++a)
            #pragma unroll
            for (int jj = 0; jj < 4; ++jj) {
                const float P = acc1[a][jj] + S * acc2[a][jj];
                const float z = sshrink(P + bv[a][jj], thr);
                const float zp = zo[a][jj];
                anychg |= ((z > 0.f) != (zp > 0.f)) | ((z < 0.f) != (zp < 0.f));
                zn[a][jj] = z;
                zo[a][jj] = z;
                const float d = z - zacc[a][jj];
                const bool live = fabsf(d) >= FLUSH;
                anylive |= live;
                const _Float16 hd = live ? (_Float16)d : (_Float16)0.0f;
                dh16[a][jj] = hd;
                zacc[a][jj] += (float)hd;
            }
        if (it == 1000) break;

        const int fw = (__any(anychg) ? 1 : 0) | (__any(anylive) ? 2 : 0);
        if (l == 0) chgs[w] = fw;
        #pragma unroll
        for (int a = 0; a < 4; ++a) {
            const unsigned lo = pack2(dh16[a][0], dh16[a][1]);
            const unsigned hi = pack2(dh16[a][2], dh16[a][3]);
            *(uint2*)&dbuf[cur][n][64 * w + 16 * a + 4 * kg] = make_uint2(lo, hi);
        }
        __syncthreads();
        const int orf = chgs[0] | chgs[1] | chgs[2] | chgs[3];
        if (!(orf & 2)) break;                        // all values f16-frozen
        stable = (orf & 1) ? 0 : stable + 1;
        if (it >= MINIT && stable >= SWIN) break;     // support+signs locked

        half8 dh[8];
        #pragma unroll
        for (int kt = 0; kt < 8; ++kt)
            dh[kt] = *(const half8*)&dbuf[cur][n][kt * 32 + kg * 8];

        #pragma unroll
        for (int kt = 0; kt < 8; ++kt)
            #pragma unroll
            for (int a = 0; a < 4; ++a) {
                acc1[a] = __builtin_amdgcn_mfma_f32_16x16x32_f16(wh[a][kt], dh[kt], acc1[a], 0, 0, 0);
                acc2[a] = __builtin_amdgcn_mfma_f32_16x16x32_f16(wl[a][kt], dh[kt], acc2[a], 0, 0, 0);
            }
        cur ^= 1;
    }

    // --- share z (z_new) across waves
    if (n < 4) {
        #pragma unroll
        for (int a = 0; a < 4; ++a) {
            float4 v = make_float4(zn[a][0], zn[a][1], zn[a][2], zn[a][3]);
            *(float4*)&znb[n][64 * w + 16 * a + 4 * kg] = v;
        }
    }
    __syncthreads();

    // --- per-wave solve: wave w handles sample s0+w
    const int sample = s0 + w;
    float* Gw = GmPool + w * (KS * (KS + 1));
    int*   idxW = idxPool + w * KS;
    float* sgnW = sgnPool + w * KS;

    const float4 zz = *(const float4*)&znb[w][4 * l];
    const int c0 = zz.x != 0.f, c1 = zz.y != 0.f, c2 = zz.z != 0.f, c3 = zz.w != 0.f;
    const int cnt = c0 + c1 + c2 + c3;
    int scan = cnt;
    for (int d = 1; d < 64; d <<= 1) {
        const int v = __shfl_up(scan, d);
        if (l >= d) scan += v;
    }
    int o = scan - cnt;
    const int k = __shfl(scan, 63);
    if (l == 0) big4[w] = (k > KS) ? 1 : 0;

    if (k == 0) {
        if (l == 0) { out[sample * 2] = 0.f; out[sample * 2 + 1] = 0.f; }
    } else if (k <= KS) {
        if (c0) { idxW[o] = 4 * l + 0; sgnW[o] = zz.x > 0.f ? 1.f : -1.f; ++o; }
        if (c1) { idxW[o] = 4 * l + 1; sgnW[o] = zz.y > 0.f ? 1.f : -1.f; ++o; }
        if (c2) { idxW[o] = 4 * l + 2; sgnW[o] = zz.z > 0.f ? 1.f : -1.f; ++o; }
        if (c3) { idxW[o] = 4 * l + 3; sgnW[o] = zz.w > 0.f ? 1.f : -1.f; ++o; }
        __builtin_amdgcn_wave_barrier();

        const int   ib = idxW[(l < k) ? l : (k - 1)];
        const float sg = (l < k) ? sgnW[l] : 0.f;
        float rhs = (l < k) ? (cbuf[sample * 256 + ib] - LAMBD * sg) : 0.f;

        for (int a = 0; a < k; ++a) {
            const int ra = __shfl(ib, a);
            if (l < k) Gw[a * (KS + 1) + l] = Gfull[ra * 256 + ib];
        }
        __builtin_amdgcn_wave_barrier();

        float dinv = 0.f;
        for (int j = 0; j < k; ++j) {
            const float Gjj = Gw[j * (KS + 1) + j];
            const float Ljj = sqrtf(fmaxf(Gjj, 1e-30f));
            const float iv = 1.0f / Ljj;
            float Laj = 0.f;
            if (l == j) { Gw[j * (KS + 1) + j] = Ljj; dinv = iv; }
            if (l > j && l < k) { Laj = Gw[l * (KS + 1) + j] * iv; Gw[l * (KS + 1) + j] = Laj; }
            __builtin_amdgcn_wave_barrier();
            for (int b = j + 1; b < k; ++b) {
                const float Lbj = Gw[b * (KS + 1) + j];
                if (l >= b && l < k) Gw[l * (KS + 1) + b] -= Laj * Lbj;
            }
            __builtin_amdgcn_wave_barrier();
        }

        float yv = rhs;
        for (int j = 0; j < k; ++j) {
            const float Laj = Gw[l * (KS + 1) + j];
            const float yjf = __shfl(yv, j) * __shfl(dinv, j);
            if (l == j) yv = yjf;
            if (l > j) yv -= Laj * yjf;
        }
        float xv = yv;
        for (int j = k - 1; j >= 0; --j) {
            const float Lja = Gw[j * (KS + 1) + l];
            const float xjf = __shfl(xv, j) * __shfl(dinv, j);
            if (l == j) xv = xjf;
            if (l < j) xv -= Lja * xjf;
        }

        float acc = (l < k) ? wg[ib] * xv : 0.f;
        for (int d = 1; d < 64; d <<= 1) acc += __shfl_xor(acc, d);
        if (l == 0) { out[sample * 2] = acc; out[sample * 2 + 1] = -acc; }
    }
    __syncthreads();

    // --- rare big-k path: block-cooperative, sequential over flagged samples
    for (int sw = 0; sw < 4; ++sw) {
        if (!big4[sw]) continue;
        const int smp = s0 + sw;
        if (w == 0) {
            const float4 z2 = *(const float4*)&znb[sw][4 * l];
            const int d0 = z2.x != 0.f, d1 = z2.y != 0.f, d2 = z2.z != 0.f, d3 = z2.w != 0.f;
            const int cn = d0 + d1 + d2 + d3;
            int sc = cn;
            for (int d = 1; d < 64; d <<= 1) {
                const int v = __shfl_up(sc, d);
                if (l >= d) sc += v;
            }
            int oo = sc - cn;
            int kk = __shfl(sc, 63);
            if (kk > KMAX) kk = KMAX;
            if (l == 0) kbig = kk;
            if (d0) { if (oo < KMAX) { idxPool[oo] = 4 * l + 0; sgnPool[oo] = z2.x > 0.f ? 1.f : -1.f; } ++oo; }
            if (d1) { if (oo < KMAX) { idxPool[oo] = 4 * l + 1; sgnPool[oo] = z2.y > 0.f ? 1.f : -1.f; } ++oo; }
            if (d2) { if (oo < KMAX) { idxPool[oo] = 4 * l + 2; sgnPool[oo] = z2.z > 0.f ? 1.f : -1.f; } ++oo; }
            if (d3) { if (oo < KMAX) { idxPool[oo] = 4 * l + 3; sgnPool[oo] = z2.w > 0.f ? 1.f : -1.f; } ++oo; }
        }
        __syncthreads();
        const int kk = kbig;
        float* Gb = GmPool;

        for (int a = 0; a < kk; ++a) {
            const int ra = idxPool[a];
            for (int b = t; b < kk; b += 256)
                Gb[a * (KMAX + 1) + b] = Gfull[ra * 256 + idxPool[b]];
        }
        for (int a = t; a < kk; a += 256)
            rhsF[a] = cbuf[smp * 256 + idxPool[a]] - LAMBD * sgnPool[a];
        __syncthreads();

        for (int j = 0; j < kk; ++j) {
            const float Ljj = sqrtf(fmaxf(Gb[j * (KMAX + 1) + j], 1e-30f));
            const float inv = 1.0f / Ljj;
            if (t == 0) Gb[j * (KMAX + 1) + j] = Ljj;
            for (int a = j + 1 + t; a < kk; a += 256)
                Gb[a * (KMAX + 1) + j] *= inv;
            __syncthreads();
            for (int b = j + 1; b < kk; ++b) {
                const float Lbj = Gb[b * (KMAX + 1) + j];
                const int a = b + t;
                if (a < kk) Gb[a * (KMAX + 1) + b] -= Gb[a * (KMAX + 1) + j] * Lbj;
            }
            __syncthreads();
        }
        for (int j = 0; j < kk; ++j) {
            const float yj = rhsF[j] / Gb[j * (KMAX + 1) + j];
            if (t == 0) solF[j] = yj;
            for (int a = j + 1 + t; a < kk; a += 256)
                rhsF[a] -= Gb[a * (KMAX + 1) + j] * yj;
            __syncthreads();
        }
        for (int j = kk - 1; j >= 0; --j) {
            const float xj = solF[j] / Gb[j * (KMAX + 1) + j];
            if (t == 0) solF[j] = xj;
            for (int a = t; a < j; a += 256)
                solF[a] -= Gb[j * (KMAX + 1) + a] * xj;
            __syncthreads();
        }
        float acc = 0.f;
        for (int a = t; a < kk; a += 256)
            acc += wg[idxPool[a]] * solF[a];
        for (int d = 1; d < 64; d <<= 1) acc += __shfl_xor(acc, d);
        if (l == 0) rhsF[64 + w] = acc;
        __syncthreads();
        if (t == 0) {
            const float tot = rhsF[64] + rhsF[65] + rhsF[66] + rhsF[67];
            out[smp * 2] = tot;
            out[smp * 2 + 1] = -tot;
        }
        __syncthreads();
    }
}

extern "C" void kernel_launch(void* const* d_in, const int* in_sizes, int n_in,
                              void* d_out, int out_size, void* d_ws, size_t ws_size,
                              hipStream_t stream) {
    const float* x = (const float*)d_in[0];   // (1024, 64)
    const float* D = (const float*)d_in[1];   // (64, 256)
    const float* w = (const float*)d_in[2];   // (256,)
    float* out = (float*)d_out;               // (1024, 2)
    float* ws  = (float*)d_ws;

    float* Gfull = ws + 256;                  // 65536 floats
    float* cbuf  = ws + 256 + 65536;          // 262144 floats

    prep_all<<<257, 256, 0, stream>>>(x, D, ws, Gfull, cbuf);
    ista_solve<<<256, 256, 0, stream>>>(cbuf, Gfull, ws, w, out);
}

// Round 12
// 229.158 us; speedup vs baseline: 1.1442x; 1.0774x over previous
//
#include <hip/hip_runtime.h>

#define LAMBD 0.2f
#define KMAX 128
#define KS 64
#define OS 1.9f      // overstep: any s < 2/L converges to the same lasso minimizer
#define ITCAP 256    // hard cap: flickering atoms beyond this are borderline,
                     // covered by refit continuity (R4/R6/R7/R11 evidence)

using half8 = __attribute__((ext_vector_type(8))) _Float16;
using f32x4 = __attribute__((ext_vector_type(4))) float;

__device__ __forceinline__ float sshrink(float v, float thr) {
    float c = fminf(fmaxf(v, -thr), thr);
    return v - c;
}

__device__ __forceinline__ unsigned pack2(_Float16 a, _Float16 b) {
    unsigned short ua = __builtin_bit_cast(unsigned short, a);
    unsigned short ub = __builtin_bit_cast(unsigned short, b);
    return (unsigned)ua | ((unsigned)ub << 16);
}

// ---------------- Kernel 1: fused prep. Block 0: s = OS/sigma_max(D)^2 (power iter).
// Blocks 1..256: Gram row r + cbuf = D^T x.
__global__ __launch_bounds__(256) void prep_all(const float* __restrict__ xg,
                                                const float* __restrict__ Dg,
                                                float* __restrict__ ws,
                                                float* __restrict__ Gfull,
                                                float* __restrict__ cbuf)
{
    const int t = threadIdx.x;
    if (blockIdx.x == 0) {
        __shared__ __align__(16) float Dc[256 * 68];
        __shared__ __align__(16) float Bm[64 * 68];
        __shared__ float vv[64];
        __shared__ float part[4 * 64];
        __shared__ float lamsh;

        for (int i = 0; i < 64; ++i)
            Dc[t * 68 + i] = Dg[i * 256 + t];
        __syncthreads();

        const int ti = t >> 4, tj = t & 15;
        float acc[4][4];
        #pragma unroll
        for (int r = 0; r < 4; ++r)
            #pragma unroll
            for (int c = 0; c < 4; ++c) acc[r][c] = 0.f;
        for (int mm = 0; mm < 256; ++mm) {
            const float4 A = *(const float4*)&Dc[mm * 68 + 4 * ti];
            const float4 Bv = *(const float4*)&Dc[mm * 68 + 4 * tj];
            const float Ae[4] = {A.x, A.y, A.z, A.w};
            const float Be[4] = {Bv.x, Bv.y, Bv.z, Bv.w};
            #pragma unroll
            for (int r = 0; r < 4; ++r)
                #pragma unroll
                for (int c = 0; c < 4; ++c)
                    acc[r][c] += Ae[r] * Be[c];
        }
        #pragma unroll
        for (int r = 0; r < 4; ++r)
            #pragma unroll
            for (int c = 0; c < 4; ++c)
                Bm[(4 * ti + r) * 68 + (4 * tj + c)] = acc[r][c];
        if (t < 64) vv[t] = 0.125f;
        __syncthreads();

        for (int itp = 0; itp < 40; ++itp) {
            const int p = t >> 6, i = t & 63;
            float partial = 0.f;
            #pragma unroll
            for (int jj = 0; jj < 16; ++jj) {
                const int j = p * 16 + jj;
                partial += Bm[j * 68 + i] * vv[j];
            }
            part[p * 64 + i] = partial;
            __syncthreads();
            if (t < 64) {
                float nv = part[t] + part[64 + t] + part[128 + t] + part[192 + t];
                float n2 = nv * nv;
                for (int d = 1; d < 64; d <<= 1) n2 += __shfl_xor(n2, d);
                vv[t] = nv * rsqrtf(n2);
                if (t == 0) lamsh = n2;
            }
            __syncthreads();
        }
        if (t == 0) ws[0] = OS / sqrtf(lamsh);   // s = OS/lambda_max(B)
    } else {
        __shared__ float xsh[4][64];
        const int r = blockIdx.x - 1;
        const int s0 = r * 4;
        xsh[t >> 6][t & 63] = xg[s0 * 64 + t];
        __syncthreads();

        float accG = 0.f, a0 = 0.f, a1 = 0.f, a2 = 0.f, a3 = 0.f;
        #pragma unroll
        for (int i = 0; i < 64; ++i) {
            const float dv = Dg[i * 256 + t];
            const float dr = Dg[i * 256 + r];
            accG += dr * dv;
            a0 += xsh[0][i] * dv;
            a1 += xsh[1][i] * dv;
            a2 += xsh[2][i] * dv;
            a3 += xsh[3][i] * dv;
        }
        Gfull[r * 256 + t] = accG;
        cbuf[(s0 + 0) * 256 + t] = a0;
        cbuf[(s0 + 1) * 256 + t] = a1;
        cbuf[(s0 + 2) * 256 + t] = a2;
        cbuf[(s0 + 3) * 256 + t] = a3;
    }
}

// ---------------- Kernel 2: overstep ISTA (MFMA delta-z), hard cap ITCAP
//                  + per-wave solve + in-block big-k fallback ----------------
__global__ __launch_bounds__(256, 1) void ista_solve(const float* __restrict__ cbuf,
                                                     const float* __restrict__ Gfull,
                                                     const float* __restrict__ ws,
                                                     const float* __restrict__ wg,
                                                     float* __restrict__ out)
{
    __shared__ __align__(16) _Float16 dbuf[2][16][264];
    __shared__ int chgs[4];
    __shared__ __align__(16) float znb[4][264];      // [sample][row]
    __shared__ __align__(16) float GmPool[16640];    // 4 x KS*(KS+1) | KMAX*(KMAX+1)
    __shared__ int   idxPool[256];
    __shared__ float sgnPool[256];
    __shared__ float rhsF[KMAX];
    __shared__ float solF[KMAX];
    __shared__ int   big4[4];
    __shared__ int   kbig;

    const int t = threadIdx.x;
    const int w = t >> 6, l = t & 63;
    const int n = l & 15, kg = l >> 4;
    const int s0 = blockIdx.x * 4;
    const float s = ws[0];
    const float thr = LAMBD * s;
    const float S = 1.0f / 2048.0f;
    const float FLUSH = 6.2e-5f;

    // --- build W = I - s*G fragments from Gfull (fp32 -> f16 hi/lo)
    half8 wh[4][8], wl[4][8];
    #pragma unroll
    for (int a = 0; a < 4; ++a) {
        const int row = 64 * w + 16 * a + n;
        #pragma unroll
        for (int kt = 0; kt < 8; ++kt) {
            const float4 g0 = *(const float4*)&Gfull[row * 256 + kt * 32 + kg * 8];
            const float4 g1 = *(const float4*)&Gfull[row * 256 + kt * 32 + kg * 8 + 4];
            const float ge[8] = {g0.x, g0.y, g0.z, g0.w, g1.x, g1.y, g1.z, g1.w};
            half8 h, lo;
            #pragma unroll
            for (int j = 0; j < 8; ++j) {
                const int col = kt * 32 + kg * 8 + j;
                const float wv = (row == col ? 1.0f : 0.0f) - s * ge[j];
                const _Float16 whj = (_Float16)wv;
                h[j] = whj;
                lo[j] = (_Float16)((wv - (float)whj) * 2048.0f);
            }
            wh[a][kt] = h;
            wl[a][kt] = lo;
        }
    }

    // --- state: zacc = sum of f16 deltas (drives P); zn = current z
    float bv[4][4], zacc[4][4], zn[4][4];
    #pragma unroll
    for (int a = 0; a < 4; ++a)
        #pragma unroll
        for (int jj = 0; jj < 4; ++jj) {
            const int row = 64 * w + 16 * a + 4 * kg + jj;
            bv[a][jj] = (n < 4) ? s * cbuf[(s0 + n) * 256 + row] : 0.f;
            zacc[a][jj] = 0.f;
        }

    f32x4 acc1[4], acc2[4];
    #pragma unroll
    for (int a = 0; a < 4; ++a) {
        acc1[a] = (f32x4){0.f, 0.f, 0.f, 0.f};
        acc2[a] = (f32x4){0.f, 0.f, 0.f, 0.f};
    }

    int cur = 0;
    for (int it = 0; ; ++it) {
        bool anylive = false;
        _Float16 dh16[4][4];
        #pragma unroll
        for (int a = 0; a < 4; ++a)
            #pragma unroll
            for (int jj = 0; jj < 4; ++jj) {
                const float P = acc1[a][jj] + S * acc2[a][jj];
                const float z = sshrink(P + bv[a][jj], thr);
                zn[a][jj] = z;
                const float d = z - zacc[a][jj];
                const bool live = fabsf(d) >= FLUSH;
                anylive |= live;
                const _Float16 hd = live ? (_Float16)d : (_Float16)0.0f;
                dh16[a][jj] = hd;
                zacc[a][jj] += (float)hd;
            }
        if (it == ITCAP) break;                       // hard cap: tail atoms are
                                                      // borderline -> refit-safe
        const int anyw = __any(anylive);
        if (l == 0) chgs[w] = anyw;
        #pragma unroll
        for (int a = 0; a < 4; ++a) {
            const unsigned lo = pack2(dh16[a][0], dh16[a][1]);
            const unsigned hi = pack2(dh16[a][2], dh16[a][3]);
            *(uint2*)&dbuf[cur][n][64 * w + 16 * a + 4 * kg] = make_uint2(lo, hi);
        }
        __syncthreads();
        if (!(chgs[0] | chgs[1] | chgs[2] | chgs[3])) break;   // all values f16-frozen

        half8 dh[8];
        #pragma unroll
        for (int kt = 0; kt < 8; ++kt)
            dh[kt] = *(const half8*)&dbuf[cur][n][kt * 32 + kg * 8];

        #pragma unroll
        for (int kt = 0; kt < 8; ++kt)
            #pragma unroll
            for (int a = 0; a < 4; ++a) {
                acc1[a] = __builtin_amdgcn_mfma_f32_16x16x32_f16(wh[a][kt], dh[kt], acc1[a], 0, 0, 0);
                acc2[a] = __builtin_amdgcn_mfma_f32_16x16x32_f16(wl[a][kt], dh[kt], acc2[a], 0, 0, 0);
            }
        cur ^= 1;
    }

    // --- share z (z_new) across waves
    if (n < 4) {
        #pragma unroll
        for (int a = 0; a < 4; ++a) {
            float4 v = make_float4(zn[a][0], zn[a][1], zn[a][2], zn[a][3]);
            *(float4*)&znb[n][64 * w + 16 * a + 4 * kg] = v;
        }
    }
    __syncthreads();

    // --- per-wave solve: wave w handles sample s0+w
    const int sample = s0 + w;
    float* Gw = GmPool + w * (KS * (KS + 1));
    int*   idxW = idxPool + w * KS;
    float* sgnW = sgnPool + w * KS;

    const float4 zz = *(const float4*)&znb[w][4 * l];
    const int c0 = zz.x != 0.f, c1 = zz.y != 0.f, c2 = zz.z != 0.f, c3 = zz.w != 0.f;
    const int cnt = c0 + c1 + c2 + c3;
    int scan = cnt;
    for (int d = 1; d < 64; d <<= 1) {
        const int v = __shfl_up(scan, d);
        if (l >= d) scan += v;
    }
    int o = scan - cnt;
    const int k = __shfl(scan, 63);
    if (l == 0) big4[w] = (k > KS) ? 1 : 0;

    if (k == 0) {
        if (l == 0) { out[sample * 2] = 0.f; out[sample * 2 + 1] = 0.f; }
    } else if (k <= KS) {
        if (c0) { idxW[o] = 4 * l + 0; sgnW[o] = zz.x > 0.f ? 1.f : -1.f; ++o; }
        if (c1) { idxW[o] = 4 * l + 1; sgnW[o] = zz.y > 0.f ? 1.f : -1.f; ++o; }
        if (c2) { idxW[o] = 4 * l + 2; sgnW[o] = zz.z > 0.f ? 1.f : -1.f; ++o; }
        if (c3) { idxW[o] = 4 * l + 3; sgnW[o] = zz.w > 0.f ? 1.f : -1.f; ++o; }
        __builtin_amdgcn_wave_barrier();

        const int   ib = idxW[(l < k) ? l : (k - 1)];
        const float sg = (l < k) ? sgnW[l] : 0.f;
        float rhs = (l < k) ? (cbuf[sample * 256 + ib] - LAMBD * sg) : 0.f;

        for (int a = 0; a < k; ++a) {
            const int ra = __shfl(ib, a);
            if (l < k) Gw[a * (KS + 1) + l] = Gfull[ra * 256 + ib];
        }
        __builtin_amdgcn_wave_barrier();

        float dinv = 0.f;
        for (int j = 0; j < k; ++j) {
            const float Gjj = Gw[j * (KS + 1) + j];
            const float Ljj = sqrtf(fmaxf(Gjj, 1e-30f));
            const float iv = 1.0f / Ljj;
            float Laj = 0.f;
            if (l == j) { Gw[j * (KS + 1) + j] = Ljj; dinv = iv; }
            if (l > j && l < k) { Laj = Gw[l * (KS + 1) + j] * iv; Gw[l * (KS + 1) + j] = Laj; }
            __builtin_amdgcn_wave_barrier();
            for (int b = j + 1; b < k; ++b) {
                const float Lbj = Gw[b * (KS + 1) + j];
                if (l >= b && l < k) Gw[l * (KS + 1) + b] -= Laj * Lbj;
            }
            __builtin_amdgcn_wave_barrier();
        }

        float yv = rhs;
        for (int j = 0; j < k; ++j) {
            const float Laj = Gw[l * (KS + 1) + j];
            const float yjf = __shfl(yv, j) * __shfl(dinv, j);
            if (l == j) yv = yjf;
            if (l > j) yv -= Laj * yjf;
        }
        float xv = yv;
        for (int j = k - 1; j >= 0; --j) {
            const float Lja = Gw[j * (KS + 1) + l];
            const float xjf = __shfl(xv, j) * __shfl(dinv, j);
            if (l == j) xv = xjf;
            if (l < j) xv -= Lja * xjf;
        }

        float acc = (l < k) ? wg[ib] * xv : 0.f;
        for (int d = 1; d < 64; d <<= 1) acc += __shfl_xor(acc, d);
        if (l == 0) { out[sample * 2] = acc; out[sample * 2 + 1] = -acc; }
    }
    __syncthreads();

    // --- rare big-k path: block-cooperative, sequential over flagged samples
    for (int sw = 0; sw < 4; ++sw) {
        if (!big4[sw]) continue;
        const int smp = s0 + sw;
        if (w == 0) {
            const float4 z2 = *(const float4*)&znb[sw][4 * l];
            const int d0 = z2.x != 0.f, d1 = z2.y != 0.f, d2 = z2.z != 0.f, d3 = z2.w != 0.f;
            const int cn = d0 + d1 + d2 + d3;
            int sc = cn;
            for (int d = 1; d < 64; d <<= 1) {
                const int v = __shfl_up(sc, d);
                if (l >= d) sc += v;
            }
            int oo = sc - cn;
            int kk = __shfl(sc, 63);
            if (kk > KMAX) kk = KMAX;
            if (l == 0) kbig = kk;
            if (d0) { if (oo < KMAX) { idxPool[oo] = 4 * l + 0; sgnPool[oo] = z2.x > 0.f ? 1.f : -1.f; } ++oo; }
            if (d1) { if (oo < KMAX) { idxPool[oo] = 4 * l + 1; sgnPool[oo] = z2.y > 0.f ? 1.f : -1.f; } ++oo; }
            if (d2) { if (oo < KMAX) { idxPool[oo] = 4 * l + 2; sgnPool[oo] = z2.z > 0.f ? 1.f : -1.f; } ++oo; }
            if (d3) { if (oo < KMAX) { idxPool[oo] = 4 * l + 3; sgnPool[oo] = z2.w > 0.f ? 1.f : -1.f; } ++oo; }
        }
        __syncthreads();
        const int kk = kbig;
        float* Gb = GmPool;

        for (int a = 0; a < kk; ++a) {
            const int ra = idxPool[a];
            for (int b = t; b < kk; b += 256)
                Gb[a * (KMAX + 1) + b] = Gfull[ra * 256 + idxPool[b]];
        }
        for (int a = t; a < kk; a += 256)
            rhsF[a] = cbuf[smp * 256 + idxPool[a]] - LAMBD * sgnPool[a];
        __syncthreads();

        for (int j = 0; j < kk; ++j) {
            const float Ljj = sqrtf(fmaxf(Gb[j * (KMAX + 1) + j], 1e-30f));
            const float inv = 1.0f / Ljj;
            if (t == 0) Gb[j * (KMAX + 1) + j] = Ljj;
            for (int a = j + 1 + t; a < kk; a += 256)
                Gb[a * (KMAX + 1) + j] *= inv;
            __syncthreads();
            for (int b = j + 1; b < kk; ++b) {
                const float Lbj = Gb[b * (KMAX + 1) + j];
                const int a = b + t;
                if (a < kk) Gb[a * (KMAX + 1) + b] -= Gb[a * (KMAX + 1) + j] * Lbj;
            }
            __syncthreads();
        }
        for (int j = 0; j < kk; ++j) {
            const float yj = rhsF[j] / Gb[j * (KMAX + 1) + j];
            if (t == 0) solF[j] = yj;
            for (int a = j + 1 + t; a < kk; a += 256)
                rhsF[a] -= Gb[a * (KMAX + 1) + j] * yj;
            __syncthreads();
        }
        for (int j = kk - 1; j >= 0; --j) {
            const float xj = solF[j] / Gb[j * (KMAX + 1) + j];
            if (t == 0) solF[j] = xj;
            for (int a = t; a < j; a += 256)
                solF[a] -= Gb[j * (KMAX + 1) + a] * xj;
            __syncthreads();
        }
        float acc = 0.f;
        for (int a = t; a < kk; a += 256)
            acc += wg[idxPool[a]] * solF[a];
        for (int d = 1; d < 64; d <<= 1) acc += __shfl_xor(acc, d);
        if (l == 0) rhsF[64 + w] = acc;
        __syncthreads();
        if (t == 0) {
            const float tot = rhsF[64] + rhsF[65] + rhsF[66] + rhsF[67];
            out[smp * 2] = tot;
            out[smp * 2 + 1] = -tot;
        }
        __syncthreads();
    }
}

extern "C" void kernel_launch(void* const* d_in, const int* in_sizes, int n_in,
                              void* d_out, int out_size, void* d_ws, size_t ws_size,
                              hipStream_t stream) {
    const float* x = (const float*)d_in[0];   // (1024, 64)
    const float* D = (const float*)d_in[1];   // (64, 256)
    const float* w = (const float*)d_in[2];   // (256,)
    float* out = (float*)d_out;               // (1024, 2)
    float* ws  = (float*)d_ws;

    float* Gfull = ws + 256;                  // 65536 floats
    float* cbuf  = ws + 256 + 65536;          // 262144 floats

    prep_all<<<257, 256, 0, stream>>>(x, D, ws, Gfull, cbuf);
    ista_solve<<<256, 256, 0, stream>>>(cbuf, Gfull, ws, w, out);
}